// Round 17
// baseline (167.071 us; speedup 1.0000x reference)
//
#include <hip/hip_runtime.h>
#include <math.h>

// Problem: B=8, C=256, H=25, W=512   (N = 26,214,400 elements)
// X/Y intermediates + transposed input in FRAGMENT-MAJOR layout:
//   F[h][blk][slot]  h=0..24 logical, blk=0..255 (b=blk>>5, w0=(blk&31)*16),
//   slot = 8192 B = 256ch x 16col bf16 in per-wave MFMA B-fragment order.
//   addr(c,w) = (c>>5)*1024 + swz(((c>>3)&3)*256 + w*16) + (c&7)*2,
//   swz(x) = x ^ (((x>>8)&1)<<5).
// ws layout (float-slot offsets):
//   Xf    @ 0          (13,107,200 slots)  scnn1 out
//   Yf    @ 13107200   (13,107,200 slots)  scnn2 out
//   Mbf   @ 26214400   (65,536 ushort)     M row-major bf16
//   coef1 @ 26247168   (512)
//   coef2 @ 26247680   (512)
//   wht   @ 26248192   (19,200)  folded conv weights [hh][c][kw]
//   --- zeroed zone (one memset: 13,312 floats) ---
//   T     @ 26267392   (12,288)
//   st1   @ 26279680   (512)
//   st2   @ 26280192   (512)
//   --- end zero zone ---
//   r     @ 26280704   (8,192)
//   Xin   @ 26288896   (13,107,200 slots)  transposed INPUT, fragment bf16
// total = 39,396,096 floats = 157,584,384 bytes of d_ws.

#define XBF_OFF    0
#define YBF_OFF    13107200
#define MBF_OFF    26214400
#define COEF1_OFF  26247168
#define COEF2_OFF  26247680
#define WH_OFF     26248192
#define T_OFF      26267392
#define ST1_OFF    26279680
#define ST2_OFF    26280192
#define R_OFF      26280704
#define XIN_OFF    26288896
#define ZERO_FLOATS 13312

typedef __attribute__((ext_vector_type(8))) short bf16x8;  // MFMA A/B frag
typedef __attribute__((ext_vector_type(4))) float f32x4;   // MFMA C/D frag

__device__ __forceinline__ ushort f2bf(float f) {          // RNE f32 -> bf16 bits
    uint32_t b = __float_as_uint(f);
    b += 0x7fffu + ((b >> 16) & 1u);
    return (ushort)(b >> 16);
}
__device__ __forceinline__ float bf2f(ushort u) {
    return __uint_as_float((uint32_t)u << 16);
}
#define UGET(v, r) ((r) == 0 ? (v).x : (r) == 1 ? (v).y : (r) == 2 ? (v).z : (v).w)

__global__ __launch_bounds__(256) void prep_mbf(const float* __restrict__ wmsg,
                                                ushort* __restrict__ Mbf)
{
    int idx = blockIdx.x * 256 + threadIdx.x;   // o*256 + i
    Mbf[idx] = f2bf(wmsg[(size_t)idx * 9 + 4]); // w_msg[o,i,4,0]
}

// wht[hh][c][kw] = sum_kh(valid) w2[hh-kh+1] * (sum_o w1[o]*w_up2[o,c,kh,kw])
__global__ __launch_bounds__(256) void prep_wh(const float* __restrict__ wup2,
                                               const float* __restrict__ w1,
                                               const float* __restrict__ w2,
                                               float* __restrict__ wht)
{
    const int c  = blockIdx.x / 3;
    const int kw = blockIdx.x % 3;
    const int o  = threadIdx.x;
    const float w1o = w1[o];
    __shared__ float red[3][256];
    red[0][o] = w1o * wup2[(size_t)((o * 256 + c) * 3 + 0) * 3 + kw];
    red[1][o] = w1o * wup2[(size_t)((o * 256 + c) * 3 + 1) * 3 + kw];
    red[2][o] = w1o * wup2[(size_t)((o * 256 + c) * 3 + 2) * 3 + kw];
    __syncthreads();
    for (int st = 128; st > 0; st >>= 1) {
        if (o < st) {
            red[0][o] += red[0][o + st];
            red[1][o] += red[1][o + st];
            red[2][o] += red[2][o + st];
        }
        __syncthreads();
    }
    if (o < 25) {     // o plays hh here
        float s = 0.f;
        #pragma unroll
        for (int kh = 0; kh < 3; ++kh) {
            int m = o - kh + 1;
            if (m >= 0 && m < 25) s = fmaf(w2[m], red[kh][0], s);
        }
        wht[(o * 256 + c) * 3 + kw] = s;   // [hh][c][kw]
    }
}

// ---------------- input transpose: planar f32 -> fragment bf16 ----------------
// Block = (b, h, 32-ch group wg). Reads the 32x512 f32 slab fully coalesced
// (2 KB rows); writes chunk wg (1 KB) of each of the 32 tiles of this (b,h).
// DENSE-STORE mapping: pass p, wave -> tile w16 = p*4 + (tid>>6); 16-lane
// group q = lane>>4 owns one 256 B block -> swz permutes WITHIN the block,
// so each wave's store is one fully dense 1 KB segment (r12's xpose split
// half its segments into 32 B pieces -> this was its 2x slowdown).
__global__ __launch_bounds__(256) void xpose(const float* __restrict__ in,
                                             ushort* __restrict__ Xin)
{
    __shared__ float tile[32][522];    // pad 522: 2-way max on transposed reads
    const int tid = threadIdx.x;
    const int bid = blockIdx.x;        // 8*25*8 = 1600
    const int b   = bid / 200;
    const int rem = bid - b * 200;
    const int h   = rem >> 3;
    const int wg  = rem & 7;           // 32-channel group == chunk index

    #pragma unroll
    for (int k = 0; k < 16; ++k) {
        int f = tid + k * 256;
        int row = f >> 7, col4 = f & 127;
        float4 v = *reinterpret_cast<const float4*>(
            in + ((size_t)((b * 256 + wg * 32 + row) * 25 + h)) * 512 + col4 * 4);
        tile[row][col4 * 4 + 0] = v.x;
        tile[row][col4 * 4 + 1] = v.y;
        tile[row][col4 * 4 + 2] = v.z;
        tile[row][col4 * 4 + 3] = v.w;
    }
    __syncthreads();

    char* outb = (char*)Xin;
    const int lane = tid & 63;
    const int q    = lane >> 4;        // 0..3 -> channels wg*32 + q*8 + j
    const int wcol = lane & 15;
    int inner = q * 256 + wcol * 16;
    inner ^= ((inner >> 8) & 1) << 5;  // swz: permutation within the 256B block
    #pragma unroll
    for (int p = 0; p < 8; ++p) {
        int w16 = p * 4 + (tid >> 6);  // one tile per wave per pass
        int w   = w16 * 16 + wcol;
        ushort us[8];
        #pragma unroll
        for (int j = 0; j < 8; ++j) us[j] = f2bf(tile[q * 8 + j][w]);
        size_t dst = ((size_t)h * 256 + b * 32 + w16) * 8192 + wg * 1024 + inner;
        uint4 pk;
        pk.x = (uint)us[0] | ((uint)us[1] << 16);
        pk.y = (uint)us[2] | ((uint)us[3] << 16);
        pk.z = (uint)us[4] | ((uint)us[5] << 16);
        pk.w = (uint)us[6] | ((uint)us[7] << 16);
        *reinterpret_cast<uint4*>(outb + dst) = pk;
    }
}

// ---------------- MFMA scan, fragment-major global I/O ----------------
// 512 thr = 8 waves, 2 o-tiles/wave, 1 block/CU, 76 VGPR (r16 structure,
// unchanged). Input is now ALWAYS fragment-dense (8 B loads). One
// lgkmcnt-only barrier per step; depth-2 x prefetch; out row h = s_{24-h}.
template <bool INBF>
__global__ __launch_bounds__(512, 2) void scnn_mfma(const void* __restrict__ xin_,
                                                    const ushort* __restrict__ Mbf,
                                                    ushort* __restrict__ outf,
                                                    const float* __restrict__ coef,
                                                    float* __restrict__ stats)
{
    __shared__ ulong2 lds_[1024];          // 16 KB: 2 x 8 KB state buffers
    char* lds = (char*)lds_;
    const char* xfr = (const char*)xin_;
    char* ofr = (char*)outf;

    const int tid   = threadIdx.x;
    const int lane  = tid & 63;
    const int wid   = tid >> 6;        // 0..7
    const int row16 = lane & 15;       // B-col == D-col == column index
    const int g     = lane >> 4;       // 0..3
    const int blk   = blockIdx.x;
    const int to0   = wid * 2;

    // LDS state read base (per-lane, swizzled); chunk kk at +kk*1024
    const int lofs = (lane * 16) ^ (((lane >> 4) & 1) << 5);
    // fragment write/read offsets (shared by LDS state AND global tiles)
    int woff[2];
    #pragma unroll
    for (int tt = 0; tt < 2; ++tt) {
        int inner = (tt * 2 + (g >> 1)) * 256 + row16 * 16 + (g & 1) * 8;
        woff[tt] = wid * 1024 + (inner ^ (((inner >> 8) & 1) << 5));
    }

    // A fragments: lane holds M[(to*16+row16)][kk*32 + g*8 .. +7]
    bf16x8 afrag[2][8];
    #pragma unroll
    for (int tt = 0; tt < 2; ++tt) {
        const ushort* mrow = Mbf + (size_t)((to0 + tt) * 16 + row16) * 256 + g * 8;
        #pragma unroll
        for (int kk = 0; kk < 8; ++kk)
            afrag[tt][kk] = *reinterpret_cast<const bf16x8*>(mrow + kk * 32);
    }

    const bool hasbn = (coef != nullptr);
    float ca[2][4], cb[2][4];
    if (hasbn) {
        #pragma unroll
        for (int tt = 0; tt < 2; ++tt)
            #pragma unroll
            for (int r = 0; r < 4; ++r) {
                int o = (to0 + tt) * 16 + g * 4 + r;
                ca[tt][r] = coef[o];
                cb[tt][r] = coef[256 + o];
            }
    }

    ushort4 xv4[2], xn4[2];
    #define LDXF(t, dst)                                                       \
        { _Pragma("unroll") for (int tt = 0; tt < 2; ++tt)                     \
              dst[tt] = *reinterpret_cast<const ushort4*>(                     \
                  xfr + ((size_t)(t) * 256 + blk) * 8192 + woff[tt]); }

    LDXF(0, xv4);
    LDXF(1, xn4);

    float s1[2][4] = {{0,0,0,0},{0,0,0,0}};
    float sq[2][4] = {{0,0,0,0},{0,0,0,0}};

    for (int t = 0; t < 25; ++t) {
        ushort4 x24[2];
        if (t < 23) LDXF(t + 2, x24);

        f32x4 acc[2] = {{0.f,0.f,0.f,0.f},{0.f,0.f,0.f,0.f}};
        if (t > 0) {
            const char* pb = lds + (t & 1) * 8192 + lofs;
            #pragma unroll
            for (int kk = 0; kk < 8; ++kk) {
                bf16x8 bfr = *reinterpret_cast<const bf16x8*>(pb + kk * 1024);
                acc[0] = __builtin_amdgcn_mfma_f32_16x16x32_bf16(afrag[0][kk], bfr, acc[0], 0, 0, 0);
                acc[1] = __builtin_amdgcn_mfma_f32_16x16x32_bf16(afrag[1][kk], bfr, acc[1], 0, 0, 0);
            }
        }

        char* wb = lds + ((t & 1) ^ 1) * 8192;
        char* ob = ofr + ((size_t)(24 - t) * 256 + blk) * 8192;   // reversed row
        #pragma unroll
        for (int tt = 0; tt < 2; ++tt) {
            ushort us[4];
            #pragma unroll
            for (int r = 0; r < 4; ++r) {
                float x = bf2f(UGET(xv4[tt], r));
                if (hasbn) x = fmaxf(fmaf(ca[tt][r], x, cb[tt][r]), 0.0f);
                float cv = x + fmaxf(acc[tt][r], 0.0f);
                us[r] = f2bf(cv);
                s1[tt][r] += cv;
                sq[tt][r] = fmaf(cv, cv, sq[tt][r]);
            }
            ushort4 u4 = make_ushort4(us[0], us[1], us[2], us[3]);
            *reinterpret_cast<ushort4*>(ob + woff[tt]) = u4;   // dense global
            *reinterpret_cast<ushort4*>(wb + woff[tt]) = u4;   // LDS state
        }

        if (t < 24) {
            // LDS-only barrier: vmcnt NOT drained (stores stay in flight).
            asm volatile("s_waitcnt lgkmcnt(0)" ::: "memory");
            __builtin_amdgcn_s_barrier();
            __builtin_amdgcn_sched_barrier(0);
        }

        #pragma unroll
        for (int tt = 0; tt < 2; ++tt) { xv4[tt] = xn4[tt]; xn4[tt] = x24[tt]; }
    }

    // fused per-channel stats: reduce across the 16 lanes sharing one o
    #pragma unroll
    for (int tt = 0; tt < 2; ++tt)
        #pragma unroll
        for (int r = 0; r < 4; ++r) {
            float a = s1[tt][r], q2 = sq[tt][r];
            #pragma unroll
            for (int m = 8; m >= 1; m >>= 1) {
                a  += __shfl_xor(a, m, 64);
                q2 += __shfl_xor(q2, m, 64);
            }
            if (row16 == 0) {
                int o = (to0 + tt) * 16 + g * 4 + r;
                atomicAdd(&stats[o], a);
                atomicAdd(&stats[256 + o], q2);
            }
        }
}

__global__ __launch_bounds__(256) void coef_kernel(const float* __restrict__ stats,
                                                   const float* __restrict__ gamma,
                                                   const float* __restrict__ beta,
                                                   float* __restrict__ coef)
{
    int c = threadIdx.x;
    float mean = stats[c] * (1.0f / 102400.0f);
    float var  = stats[256 + c] * (1.0f / 102400.0f) - mean * mean;
    float a = gamma[c] * rsqrtf(var + 1e-5f);
    coef[c] = a;
    coef[256 + c] = beta[c] - mean * a;
}

// T[kw][b][v] = sum_{c,hh} wht[hh,c,kw] * relu(bn2(Y)), Y in FRAGMENT layout.
__global__ __launch_bounds__(512) void conv_reduce(const ushort* __restrict__ Yf_,
                                                   const float* __restrict__ coef2,
                                                   const float* __restrict__ wht,
                                                   float* __restrict__ T)
{
    const char* Yf = (const char*)Yf_;
    const int tid   = threadIdx.x;
    const int lane  = tid & 63;
    const int wid   = tid >> 6;
    const int row16 = lane & 15;
    const int g     = lane >> 4;
    const int blk   = blockIdx.x;
    const int b     = blk >> 5;
    const int w0    = (blk & 31) << 4;
    const int to0   = wid * 2;

    int woff[2], ch0[2];
    #pragma unroll
    for (int tt = 0; tt < 2; ++tt) {
        int inner = (tt * 2 + (g >> 1)) * 256 + row16 * 16 + (g & 1) * 8;
        woff[tt] = wid * 1024 + (inner ^ (((inner >> 8) & 1) << 5));
        ch0[tt]  = (to0 + tt) * 16 + g * 4;
    }

    float a2[2][4], b2[2][4];
    #pragma unroll
    for (int tt = 0; tt < 2; ++tt)
        #pragma unroll
        for (int r = 0; r < 4; ++r) {
            a2[tt][r] = coef2[ch0[tt] + r];
            b2[tt][r] = coef2[256 + ch0[tt] + r];
        }

    float acc0 = 0.f, acc1 = 0.f, acc2 = 0.f;
    for (int h = 0; h < 25; ++h) {
        #pragma unroll
        for (int tt = 0; tt < 2; ++tt) {
            ushort4 y4 = *reinterpret_cast<const ushort4*>(
                Yf + ((size_t)h * 256 + blk) * 8192 + woff[tt]);
            const float* wb = wht + ((size_t)h * 256 + ch0[tt]) * 3;
            float4 qa = *reinterpret_cast<const float4*>(wb);
            float4 qb = *reinterpret_cast<const float4*>(wb + 4);
            float4 qc = *reinterpret_cast<const float4*>(wb + 8);
            float A[12] = {qa.x, qa.y, qa.z, qa.w, qb.x, qb.y,
                           qb.z, qb.w, qc.x, qc.y, qc.z, qc.w};
            #pragma unroll
            for (int r = 0; r < 4; ++r) {
                float z = fmaxf(fmaf(a2[tt][r], bf2f(UGET(y4, r)), b2[tt][r]), 0.f);
                acc0 = fmaf(A[r * 3 + 0], z, acc0);
                acc1 = fmaf(A[r * 3 + 1], z, acc1);
                acc2 = fmaf(A[r * 3 + 2], z, acc2);
            }
        }
    }

    acc0 += __shfl_xor(acc0, 16, 64); acc0 += __shfl_xor(acc0, 32, 64);
    acc1 += __shfl_xor(acc1, 16, 64); acc1 += __shfl_xor(acc1, 32, 64);
    acc2 += __shfl_xor(acc2, 16, 64); acc2 += __shfl_xor(acc2, 32, 64);

    __shared__ float red[8][3][16];
    if (lane < 16) {
        red[wid][0][lane] = acc0;
        red[wid][1][lane] = acc1;
        red[wid][2][lane] = acc2;
    }
    __syncthreads();
    if (tid < 48) {
        int kw = tid >> 4, col = tid & 15;
        float s = 0.f;
        #pragma unroll
        for (int w8 = 0; w8 < 8; ++w8) s += red[w8][kw][col];
        T[(size_t)(kw * 8 + b) * 512 + w0 + col] = s;
    }
}

// r[b,w'] = sum_kw (valid u=w'+kw-1) interp_512->1024(T[kw][b])[u]
__global__ __launch_bounds__(256) void combine_r(const float* __restrict__ T,
                                                 float* __restrict__ r)
{
    int idx = blockIdx.x * 256 + threadIdx.x;   // 8192
    int b = idx >> 10, w = idx & 1023;
    const float scale = (float)(511.0 / 1023.0);
    float acc = 0.f;
    #pragma unroll
    for (int kw = 0; kw < 3; ++kw) {
        int u = w + kw - 1;
        if (u >= 0 && u < 1024) {
            float pos = (float)u * scale;
            int i0 = (int)pos;
            float f = pos - (float)i0;
            int i1 = min(i0 + 1, 511);
            const float* Tk = T + (size_t)(kw * 8 + b) * 512;
            float lo = Tk[i0];
            acc += fmaf(Tk[i1] - lo, f, lo);
        }
    }
    r[idx] = acc;
}

// out[b,w4] = sigmoid( up_{2048->4096}( up_{1024->2048}(r) ) )
__global__ __launch_bounds__(256) void final_kernel(const float* __restrict__ r,
                                                    float* __restrict__ out)
{
    int idx = blockIdx.x * 256 + threadIdx.x;   // 32768
    int b = idx >> 12, w4 = idx & 4095;
    const float s3 = (float)(2047.0 / 4095.0);
    const float s2 = (float)(1023.0 / 2047.0);
    const float* rb = r + b * 1024;

    float pos3 = (float)w4 * s3;
    int j0 = (int)pos3;
    float f3 = pos3 - (float)j0;
    int j1 = min(j0 + 1, 2047);

    float v[2];
    int jj[2] = {j0, j1};
    #pragma unroll
    for (int k = 0; k < 2; ++k) {
        float p = (float)jj[k] * s2;
        int i = (int)p;
        float f = p - (float)i;
        int i2 = min(i + 1, 1023);
        float lo = rb[i];
        v[k] = fmaf(rb[i2] - lo, f, lo);
    }
    float z = fmaf(v[1] - v[0], f3, v[0]);
    out[idx] = 1.0f / (1.0f + expf(-z));
}

extern "C" void kernel_launch(void* const* d_in, const int* in_sizes, int n_in,
                              void* d_out, int out_size, void* d_ws, size_t ws_size,
                              hipStream_t stream)
{
    const float* p2c   = (const float*)d_in[0];
    const float* wmsg  = (const float*)d_in[1];
    const float* gamma = (const float*)d_in[2];
    const float* beta  = (const float*)d_in[3];
    const float* wup2  = (const float*)d_in[4];
    const float* wc1   = (const float*)d_in[5];
    const float* wc2   = (const float*)d_in[6];
    float* out = (float*)d_out;
    float* ws  = (float*)d_ws;

    ushort* Xf    = (ushort*)(ws + XBF_OFF);
    ushort* Yf    = (ushort*)(ws + YBF_OFF);
    ushort* Mbf   = (ushort*)(ws + MBF_OFF);
    float*  coef1 = ws + COEF1_OFF;
    float*  coef2 = ws + COEF2_OFF;
    float*  wht   = ws + WH_OFF;
    float*  T     = ws + T_OFF;
    float*  st1   = ws + ST1_OFF;
    float*  st2   = ws + ST2_OFF;
    float*  r     = ws + R_OFF;
    ushort* Xin   = (ushort*)(ws + XIN_OFF);

    hipMemsetAsync(T, 0, ZERO_FLOATS * sizeof(float), stream);  // T, st1, st2

    prep_mbf<<<256, 256, 0, stream>>>(wmsg, Mbf);
    prep_wh<<<768, 256, 0, stream>>>(wup2, wc1, wc2, wht);

    // input transpose: planar f32 -> fragment bf16 (dense both sides)
    xpose<<<1600, 256, 0, stream>>>(p2c, Xin);

    // scnn1: fragment input -> Xf (fragment, logical order) + stats
    scnn_mfma<true><<<256, 512, 0, stream>>>(Xin, Mbf, Xf, nullptr, st1);
    coef_kernel<<<1, 256, 0, stream>>>(st1, gamma, beta, coef1);

    // scnn2: reads relu(bn1(Xf)) fragment-dense -> Yf + stats
    scnn_mfma<true><<<256, 512, 0, stream>>>(Xf, Mbf, Yf, coef1, st2);
    coef_kernel<<<1, 256, 0, stream>>>(st2, gamma, beta, coef2);

    // folded conv + h-reduction on fragment layout
    conv_reduce<<<256, 512, 0, stream>>>(Yf, coef2, wht, T);
    combine_r<<<32, 256, 0, stream>>>(T, r);

    // two upsamples + sigmoid
    final_kernel<<<128, 256, 0, stream>>>(r, out);
}

// Round 18
// 150.260 us; speedup vs baseline: 1.1119x; 1.1119x over previous
//
#include <hip/hip_runtime.h>
#include <math.h>

// Problem: B=8, C=256, H=25, W=512   (N = 26,214,400 elements)
// X/Y intermediates in FRAGMENT-MAJOR layout:
//   F[h][blk][slot]  h=0..24 logical, blk=0..255 (b=blk>>5, w0=(blk&31)*16),
//   slot = 8192 B = 256ch x 16col bf16 in per-wave MFMA B-fragment order
//   (byte offsets identical to the scnn kernel's LDS state buffer, incl swizzle).
// ws layout (float-slot offsets):
//   Xf    @ 0          (13,107,200 slots)  scnn1 out
//   Yf    @ 13107200   (13,107,200 slots)  scnn2 out
//   Mbf   @ 26214400   (65,536 ushort)     M row-major bf16
//   coef1 @ 26247168   (512)
//   coef2 @ 26247680   (512)
//   wht   @ 26248192   (19,200)  folded conv weights [hh][c][kw]
//   --- zeroed zone (one memset: 13,312 floats) ---
//   T     @ 26267392   (12,288)
//   st1   @ 26279680   (512)
//   st2   @ 26280192   (512)
//   --- end zero zone ---
//   r     @ 26280704   (8,192)
// total = 26,288,896 floats = 105,155,584 bytes of d_ws.

#define XBF_OFF    0
#define YBF_OFF    13107200
#define MBF_OFF    26214400
#define COEF1_OFF  26247168
#define COEF2_OFF  26247680
#define WH_OFF     26248192
#define T_OFF      26267392
#define ST1_OFF    26279680
#define ST2_OFF    26280192
#define R_OFF      26280704
#define ZERO_FLOATS 13312

typedef __attribute__((ext_vector_type(8))) short bf16x8;  // MFMA A/B frag
typedef __attribute__((ext_vector_type(4))) float f32x4;   // MFMA C/D frag

__device__ __forceinline__ ushort f2bf(float f) {          // RNE f32 -> bf16 bits
    uint32_t b = __float_as_uint(f);
    b += 0x7fffu + ((b >> 16) & 1u);
    return (ushort)(b >> 16);
}
__device__ __forceinline__ float bf2f(ushort u) {
    return __uint_as_float((uint32_t)u << 16);
}
#define UGET(v, r) ((r) == 0 ? (v).x : (r) == 1 ? (v).y : (r) == 2 ? (v).z : (v).w)

__global__ __launch_bounds__(256) void prep_mbf(const float* __restrict__ wmsg,
                                                ushort* __restrict__ Mbf)
{
    int idx = blockIdx.x * 256 + threadIdx.x;   // o*256 + i
    Mbf[idx] = f2bf(wmsg[(size_t)idx * 9 + 4]); // w_msg[o,i,4,0]
}

// wht[hh][c][kw] = sum_kh(valid) w2[hh-kh+1] * (sum_o w1[o]*w_up2[o,c,kh,kw])
__global__ __launch_bounds__(256) void prep_wh(const float* __restrict__ wup2,
                                               const float* __restrict__ w1,
                                               const float* __restrict__ w2,
                                               float* __restrict__ wht)
{
    const int c  = blockIdx.x / 3;
    const int kw = blockIdx.x % 3;
    const int o  = threadIdx.x;
    const float w1o = w1[o];
    __shared__ float red[3][256];
    red[0][o] = w1o * wup2[(size_t)((o * 256 + c) * 3 + 0) * 3 + kw];
    red[1][o] = w1o * wup2[(size_t)((o * 256 + c) * 3 + 1) * 3 + kw];
    red[2][o] = w1o * wup2[(size_t)((o * 256 + c) * 3 + 2) * 3 + kw];
    __syncthreads();
    for (int st = 128; st > 0; st >>= 1) {
        if (o < st) {
            red[0][o] += red[0][o + st];
            red[1][o] += red[1][o + st];
            red[2][o] += red[2][o + st];
        }
        __syncthreads();
    }
    if (o < 25) {     // o plays hh here
        float s = 0.f;
        #pragma unroll
        for (int kh = 0; kh < 3; ++kh) {
            int m = o - kh + 1;
            if (m >= 0 && m < 25) s = fmaf(w2[m], red[kh][0], s);
        }
        wht[(o * 256 + c) * 3 + kw] = s;   // [hh][c][kw]
    }
}

// ---------------- MFMA scan, fragment-major global I/O ----------------
// 512 thr = 8 waves, 2 o-tiles/wave, 1 block/CU, 76 VGPR. Global output
// stores are the SAME ushort4 written to the LDS state buffer, at byte
// offset woff within a dense 8 KB tile F[h][blk] (2 x 512 B dense per wave).
// scnn2's x loads read identical offsets -> dense 8 B loads. One
// lgkmcnt-only barrier per step (vmcnt never drained in-loop); depth-2
// x prefetch. out row h gets s_{24-h} (reference's reversed order).
template <bool INBF>
__global__ __launch_bounds__(512, 2) void scnn_mfma(const void* __restrict__ xin_,
                                                    const ushort* __restrict__ Mbf,
                                                    ushort* __restrict__ outf,
                                                    const float* __restrict__ coef,
                                                    float* __restrict__ stats)
{
    __shared__ ulong2 lds_[1024];          // 16 KB: 2 x 8 KB state buffers
    char* lds = (char*)lds_;
    const float* xf  = (const float*)xin_;  // planar f32 (scnn1)
    const char*  xfr = (const char*)xin_;   // fragment layout (scnn2)
    char* ofr = (char*)outf;

    const int tid   = threadIdx.x;
    const int lane  = tid & 63;
    const int wid   = tid >> 6;        // 0..7
    const int row16 = lane & 15;       // B-col == D-col == column index
    const int g     = lane >> 4;       // 0..3
    const int blk   = blockIdx.x;
    const int b     = blk >> 5;
    const int w0    = (blk & 31) << 4;
    const int to0   = wid * 2;

    // LDS state read base (per-lane, swizzled); chunk kk at +kk*1024
    const int lofs = (lane * 16) ^ (((lane >> 4) & 1) << 5);
    // fragment write/read offsets (shared by LDS state AND global tiles)
    int woff[2];
    #pragma unroll
    for (int tt = 0; tt < 2; ++tt) {
        int inner = (tt * 2 + (g >> 1)) * 256 + row16 * 16 + (g & 1) * 8;
        woff[tt] = wid * 1024 + (inner ^ (((inner >> 8) & 1) << 5));
    }

    // A fragments: lane holds M[(to*16+row16)][kk*32 + g*8 .. +7]
    bf16x8 afrag[2][8];
    #pragma unroll
    for (int tt = 0; tt < 2; ++tt) {
        const ushort* mrow = Mbf + (size_t)((to0 + tt) * 16 + row16) * 256 + g * 8;
        #pragma unroll
        for (int kk = 0; kk < 8; ++kk)
            afrag[tt][kk] = *reinterpret_cast<const bf16x8*>(mrow + kk * 32);
    }

    const bool hasbn = (coef != nullptr);
    float ca[2][4], cb[2][4];
    if (hasbn) {
        #pragma unroll
        for (int tt = 0; tt < 2; ++tt)
            #pragma unroll
            for (int r = 0; r < 4; ++r) {
                int o = (to0 + tt) * 16 + g * 4 + r;
                ca[tt][r] = coef[o];
                cb[tt][r] = coef[256 + o];
            }
    }

    // planar input offsets (scnn1 only)
    uint ofsP[2][4];
    if (!INBF) {
        #pragma unroll
        for (int tt = 0; tt < 2; ++tt)
            #pragma unroll
            for (int r = 0; r < 4; ++r) {
                int o = (to0 + tt) * 16 + g * 4 + r;
                ofsP[tt][r] = (uint)((b * 256 + o) * 12800 + w0 + row16);
            }
    }

    // x prefetch state (raw bits; convert at use)
    uint    xv[2][4], xn[2][4];       // scnn1: f32 bits
    ushort4 xv4[2], xn4[2];           // scnn2: frag bf16x4

    #define LDXP(t, dst)                                                       \
        { _Pragma("unroll") for (int tt = 0; tt < 2; ++tt)                     \
          _Pragma("unroll") for (int r = 0; r < 4; ++r)                        \
              dst[tt][r] = __float_as_uint(xf[ofsP[tt][r] + (uint)(t) * 512u]); }
    #define LDXF(t, dst)                                                       \
        { _Pragma("unroll") for (int tt = 0; tt < 2; ++tt)                     \
              dst[tt] = *reinterpret_cast<const ushort4*>(                     \
                  xfr + ((size_t)(t) * 256 + blk) * 8192 + woff[tt]); }

    if (INBF) { LDXF(0, xv4); LDXF(1, xn4); }
    else      { LDXP(0, xv);  LDXP(1, xn);  }

    float s1[2][4] = {{0,0,0,0},{0,0,0,0}};
    float sq[2][4] = {{0,0,0,0},{0,0,0,0}};

    for (int t = 0; t < 25; ++t) {
        uint    x2[2][4];
        ushort4 x24[2];
        if (t < 23) { if (INBF) { LDXF(t + 2, x24); } else { LDXP(t + 2, x2); } }

        f32x4 acc[2] = {{0.f,0.f,0.f,0.f},{0.f,0.f,0.f,0.f}};
        if (t > 0) {
            const char* pb = lds + (t & 1) * 8192 + lofs;
            #pragma unroll
            for (int kk = 0; kk < 8; ++kk) {
                bf16x8 bfr = *reinterpret_cast<const bf16x8*>(pb + kk * 1024);
                acc[0] = __builtin_amdgcn_mfma_f32_16x16x32_bf16(afrag[0][kk], bfr, acc[0], 0, 0, 0);
                acc[1] = __builtin_amdgcn_mfma_f32_16x16x32_bf16(afrag[1][kk], bfr, acc[1], 0, 0, 0);
            }
        }

        char* wb = lds + ((t & 1) ^ 1) * 8192;
        char* ob = ofr + ((size_t)(24 - t) * 256 + blk) * 8192;   // reversed row
        #pragma unroll
        for (int tt = 0; tt < 2; ++tt) {
            ushort us[4];
            #pragma unroll
            for (int r = 0; r < 4; ++r) {
                float x = INBF ? bf2f(UGET(xv4[tt], r))
                               : __uint_as_float(xv[tt][r]);
                if (hasbn) x = fmaxf(fmaf(ca[tt][r], x, cb[tt][r]), 0.0f);
                float cv = x + fmaxf(acc[tt][r], 0.0f);
                us[r] = f2bf(cv);
                s1[tt][r] += cv;
                sq[tt][r] = fmaf(cv, cv, sq[tt][r]);
            }
            ushort4 u4 = make_ushort4(us[0], us[1], us[2], us[3]);
            *reinterpret_cast<ushort4*>(ob + woff[tt]) = u4;   // dense global
            *reinterpret_cast<ushort4*>(wb + woff[tt]) = u4;   // LDS state
        }

        if (t < 24) {
            // LDS-only barrier: vmcnt NOT drained (stores stay in flight).
            asm volatile("s_waitcnt lgkmcnt(0)" ::: "memory");
            __builtin_amdgcn_s_barrier();
            __builtin_amdgcn_sched_barrier(0);
        }

        if (INBF) {
            #pragma unroll
            for (int tt = 0; tt < 2; ++tt) { xv4[tt] = xn4[tt]; xn4[tt] = x24[tt]; }
        } else {
            #pragma unroll
            for (int tt = 0; tt < 2; ++tt)
                #pragma unroll
                for (int r = 0; r < 4; ++r) { xv[tt][r] = xn[tt][r]; xn[tt][r] = x2[tt][r]; }
        }
    }

    // fused per-channel stats: reduce across the 16 lanes sharing one o
    #pragma unroll
    for (int tt = 0; tt < 2; ++tt)
        #pragma unroll
        for (int r = 0; r < 4; ++r) {
            float a = s1[tt][r], q2 = sq[tt][r];
            #pragma unroll
            for (int m = 8; m >= 1; m >>= 1) {
                a  += __shfl_xor(a, m, 64);
                q2 += __shfl_xor(q2, m, 64);
            }
            if (row16 == 0) {
                int o = (to0 + tt) * 16 + g * 4 + r;
                atomicAdd(&stats[o], a);
                atomicAdd(&stats[256 + o], q2);
            }
        }
}

__global__ __launch_bounds__(256) void coef_kernel(const float* __restrict__ stats,
                                                   const float* __restrict__ gamma,
                                                   const float* __restrict__ beta,
                                                   float* __restrict__ coef)
{
    int c = threadIdx.x;
    float mean = stats[c] * (1.0f / 102400.0f);
    float var  = stats[256 + c] * (1.0f / 102400.0f) - mean * mean;
    float a = gamma[c] * rsqrtf(var + 1e-5f);
    coef[c] = a;
    coef[256 + c] = beta[c] - mean * a;
}

// T[kw][b][v] = sum_{c,hh} wht[hh,c,kw] * relu(bn2(Y)), Y in FRAGMENT layout.
// Thread geometry mirrors the scnn writer: thread (wid,g,row16) reads its own
// 2 ushort4 slots per h (dense 8 B loads), owns channels (wid*2+tt)*16+g*4+r,
// column w0+row16. Reduction: shfl over lanes sharing row16, LDS over waves,
// plain stores to T (each (b,v) written by exactly one block).
__global__ __launch_bounds__(512) void conv_reduce(const ushort* __restrict__ Yf_,
                                                   const float* __restrict__ coef2,
                                                   const float* __restrict__ wht,
                                                   float* __restrict__ T)
{
    const char* Yf = (const char*)Yf_;
    const int tid   = threadIdx.x;
    const int lane  = tid & 63;
    const int wid   = tid >> 6;
    const int row16 = lane & 15;
    const int g     = lane >> 4;
    const int blk   = blockIdx.x;
    const int b     = blk >> 5;
    const int w0    = (blk & 31) << 4;
    const int to0   = wid * 2;

    int woff[2], ch0[2];
    #pragma unroll
    for (int tt = 0; tt < 2; ++tt) {
        int inner = (tt * 2 + (g >> 1)) * 256 + row16 * 16 + (g & 1) * 8;
        woff[tt] = wid * 1024 + (inner ^ (((inner >> 8) & 1) << 5));
        ch0[tt]  = (to0 + tt) * 16 + g * 4;
    }

    float a2[2][4], b2[2][4];
    #pragma unroll
    for (int tt = 0; tt < 2; ++tt)
        #pragma unroll
        for (int r = 0; r < 4; ++r) {
            a2[tt][r] = coef2[ch0[tt] + r];
            b2[tt][r] = coef2[256 + ch0[tt] + r];
        }

    float acc0 = 0.f, acc1 = 0.f, acc2 = 0.f;
    for (int h = 0; h < 25; ++h) {
        #pragma unroll
        for (int tt = 0; tt < 2; ++tt) {
            ushort4 y4 = *reinterpret_cast<const ushort4*>(
                Yf + ((size_t)h * 256 + blk) * 8192 + woff[tt]);
            const float* wb = wht + ((size_t)h * 256 + ch0[tt]) * 3;
            float4 qa = *reinterpret_cast<const float4*>(wb);
            float4 qb = *reinterpret_cast<const float4*>(wb + 4);
            float4 qc = *reinterpret_cast<const float4*>(wb + 8);
            float A[12] = {qa.x, qa.y, qa.z, qa.w, qb.x, qb.y,
                           qb.z, qb.w, qc.x, qc.y, qc.z, qc.w};
            #pragma unroll
            for (int r = 0; r < 4; ++r) {
                float z = fmaxf(fmaf(a2[tt][r], bf2f(UGET(y4, r)), b2[tt][r]), 0.f);
                acc0 = fmaf(A[r * 3 + 0], z, acc0);
                acc1 = fmaf(A[r * 3 + 1], z, acc1);
                acc2 = fmaf(A[r * 3 + 2], z, acc2);
            }
        }
    }

    acc0 += __shfl_xor(acc0, 16, 64); acc0 += __shfl_xor(acc0, 32, 64);
    acc1 += __shfl_xor(acc1, 16, 64); acc1 += __shfl_xor(acc1, 32, 64);
    acc2 += __shfl_xor(acc2, 16, 64); acc2 += __shfl_xor(acc2, 32, 64);

    __shared__ float red[8][3][16];
    if (lane < 16) {
        red[wid][0][lane] = acc0;
        red[wid][1][lane] = acc1;
        red[wid][2][lane] = acc2;
    }
    __syncthreads();
    if (tid < 48) {
        int kw = tid >> 4, col = tid & 15;
        float s = 0.f;
        #pragma unroll
        for (int w8 = 0; w8 < 8; ++w8) s += red[w8][kw][col];
        T[(size_t)(kw * 8 + b) * 512 + w0 + col] = s;
    }
}

// r[b,w'] = sum_kw (valid u=w'+kw-1) interp_512->1024(T[kw][b])[u]
__global__ __launch_bounds__(256) void combine_r(const float* __restrict__ T,
                                                 float* __restrict__ r)
{
    int idx = blockIdx.x * 256 + threadIdx.x;   // 8192
    int b = idx >> 10, w = idx & 1023;
    const float scale = (float)(511.0 / 1023.0);
    float acc = 0.f;
    #pragma unroll
    for (int kw = 0; kw < 3; ++kw) {
        int u = w + kw - 1;
        if (u >= 0 && u < 1024) {
            float pos = (float)u * scale;
            int i0 = (int)pos;
            float f = pos - (float)i0;
            int i1 = min(i0 + 1, 511);
            const float* Tk = T + (size_t)(kw * 8 + b) * 512;
            float lo = Tk[i0];
            acc += fmaf(Tk[i1] - lo, f, lo);
        }
    }
    r[idx] = acc;
}

// out[b,w4] = sigmoid( up_{2048->4096}( up_{1024->2048}(r) ) )
__global__ __launch_bounds__(256) void final_kernel(const float* __restrict__ r,
                                                    float* __restrict__ out)
{
    int idx = blockIdx.x * 256 + threadIdx.x;   // 32768
    int b = idx >> 12, w4 = idx & 4095;
    const float s3 = (float)(2047.0 / 4095.0);
    const float s2 = (float)(1023.0 / 2047.0);
    const float* rb = r + b * 1024;

    float pos3 = (float)w4 * s3;
    int j0 = (int)pos3;
    float f3 = pos3 - (float)j0;
    int j1 = min(j0 + 1, 2047);

    float v[2];
    int jj[2] = {j0, j1};
    #pragma unroll
    for (int k = 0; k < 2; ++k) {
        float p = (float)jj[k] * s2;
        int i = (int)p;
        float f = p - (float)i;
        int i2 = min(i + 1, 1023);
        float lo = rb[i];
        v[k] = fmaf(rb[i2] - lo, f, lo);
    }
    float z = fmaf(v[1] - v[0], f3, v[0]);
    out[idx] = 1.0f / (1.0f + expf(-z));
}

extern "C" void kernel_launch(void* const* d_in, const int* in_sizes, int n_in,
                              void* d_out, int out_size, void* d_ws, size_t ws_size,
                              hipStream_t stream)
{
    const float* p2c   = (const float*)d_in[0];
    const float* wmsg  = (const float*)d_in[1];
    const float* gamma = (const float*)d_in[2];
    const float* beta  = (const float*)d_in[3];
    const float* wup2  = (const float*)d_in[4];
    const float* wc1   = (const float*)d_in[5];
    const float* wc2   = (const float*)d_in[6];
    float* out = (float*)d_out;
    float* ws  = (float*)d_ws;

    ushort* Xf    = (ushort*)(ws + XBF_OFF);
    ushort* Yf    = (ushort*)(ws + YBF_OFF);
    ushort* Mbf   = (ushort*)(ws + MBF_OFF);
    float*  coef1 = ws + COEF1_OFF;
    float*  coef2 = ws + COEF2_OFF;
    float*  wht   = ws + WH_OFF;
    float*  T     = ws + T_OFF;
    float*  st1   = ws + ST1_OFF;
    float*  st2   = ws + ST2_OFF;
    float*  r     = ws + R_OFF;

    hipMemsetAsync(T, 0, ZERO_FLOATS * sizeof(float), stream);  // T, st1, st2

    prep_mbf<<<256, 256, 0, stream>>>(wmsg, Mbf);
    prep_wh<<<768, 256, 0, stream>>>(wup2, wc1, wc2, wht);

    // scnn1: planar f32 input -> Xf (fragment layout, logical order) + stats
    scnn_mfma<false><<<256, 512, 0, stream>>>(p2c, Mbf, Xf, nullptr, st1);
    coef_kernel<<<1, 256, 0, stream>>>(st1, gamma, beta, coef1);

    // scnn2: reads relu(bn1(Xf)) fragment-dense -> Yf + stats
    scnn_mfma<true><<<256, 512, 0, stream>>>(Xf, Mbf, Yf, coef1, st2);
    coef_kernel<<<1, 256, 0, stream>>>(st2, gamma, beta, coef2);

    // folded conv + h-reduction on fragment layout
    conv_reduce<<<256, 512, 0, stream>>>(Yf, coef2, wht, T);
    combine_r<<<32, 256, 0, stream>>>(T, r);

    // two upsamples + sigmoid
    final_kernel<<<128, 256, 0, stream>>>(r, out);
}